// Round 17
// baseline (176.514 us; speedup 1.0000x reference)
//
#include <hip/hip_runtime.h>
#include <hip/hip_bf16.h>
#include <hip/hip_fp16.h>
#include <float.h>

#define F 128          // hidden = H*C
#define HEADS 4
#define CPH 32

// bucket sort params: bucket = dst>>7 (N=50000 <= 65536), 512 buckets,
// G=64 edge-chunk blocks -> counts matrix 512x64 = 32768.
#define NB 512
#define BSHIFT 7
#define G 64
#define SEGCAP 5120    // LDS staging cap for a bucket segment (mean 1562, P(>5120)~0)

using f16x2 = __attribute__((ext_vector_type(2))) _Float16;
using f16x8 = __attribute__((ext_vector_type(8))) _Float16;
using f32x4 = __attribute__((ext_vector_type(4))) float;

// ---------------- fused bucket-hist + weight/att convert + last-block scan ----------
// blocks 0..G-1: per-block bucket histogram; the LAST hist block to finish also
// performs the 32768-entry exclusive scan (saves a dispatch). done must be 0 at
// entry (4B memset graph node). blocks G..G+63: W->W^T fp16. block G+64: att conv.

__global__ __launch_bounds__(1024) void hist_convw_scan_kernel(
    const int* __restrict__ dst, int* __restrict__ counts, int E, int chunk,
    const float* __restrict__ W0, const float* __restrict__ W1,
    const float* __restrict__ W2, const float* __restrict__ W3,
    _Float16* __restrict__ T0, _Float16* __restrict__ T1,
    _Float16* __restrict__ T2, _Float16* __restrict__ T3,
    const float* __restrict__ att1, const float* __restrict__ att2,
    _Float16* __restrict__ attH1, _Float16* __restrict__ attH2,
    int* __restrict__ done, int* __restrict__ offsets)
{
    __shared__ int smem[1024];
    __shared__ int ticket;
    if (blockIdx.x < G) {
        int blk = blockIdx.x;
        for (int b = threadIdx.x; b < NB; b += 1024) smem[b] = 0;
        __syncthreads();
        int e0 = blk * chunk, e1 = min(e0 + chunk, E);
        for (int e = e0 + threadIdx.x; e < e1; e += 1024)
            atomicAdd(&smem[dst[e] >> BSHIFT], 1);
        __syncthreads();
        for (int b = threadIdx.x; b < NB; b += 1024)
            counts[b * G + blk] = smem[b];
        // last hist block runs the scan
        __threadfence();
        __syncthreads();
        if (threadIdx.x == 0) ticket = atomicAdd(done, 1);
        __syncthreads();
        if (ticket == G - 1) {
            __threadfence();
            int t = threadIdx.x;
            int loc[32];
            int s = 0;
            #pragma unroll
            for (int j = 0; j < 32; ++j) { loc[j] = s; s += counts[t * 32 + j]; }
            smem[t] = s;
            __syncthreads();
            for (int o = 1; o < 1024; o <<= 1) {
                int a = (t >= o) ? smem[t - o] : 0;
                __syncthreads();
                smem[t] += a;
                __syncthreads();
            }
            int excl = smem[t] - s;
            #pragma unroll
            for (int j = 0; j < 32; ++j) offsets[t * 32 + j] = excl + loc[j];
        }
    } else if (blockIdx.x < G + 64) {
        int b = blockIdx.x - G;                       // 0..63
        int m = b >> 4;
        int tid = (b & 15) * 1024 + threadIdx.x;      // 0..16383 = n*128+k
        int n = tid >> 7, k = tid & 127;
        const float* W = m == 0 ? W0 : m == 1 ? W1 : m == 2 ? W2 : W3;
        _Float16*    T = m == 0 ? T0 : m == 1 ? T1 : m == 2 ? T2 : T3;
        T[tid] = (_Float16)W[k * F + n];
    } else {
        if (threadIdx.x < 128)      attH1[threadIdx.x] = (_Float16)att1[threadIdx.x];
        else if (threadIdx.x < 256) attH2[threadIdx.x - 128] = (_Float16)att2[threadIdx.x - 128];
    }
}

// pass C: scatter PACKED (src<<7)|(dst&127) into bucket-sorted order (4B/edge)
__global__ __launch_bounds__(1024) void bucket_scatter_kernel(
    const int* __restrict__ src, const int* __restrict__ dst,
    const int* __restrict__ offsets, unsigned* __restrict__ pairs, int E, int chunk)
{
    __shared__ int curs[NB];
    int blk = blockIdx.x;
    for (int b = threadIdx.x; b < NB; b += 1024) curs[b] = offsets[b * G + blk];
    __syncthreads();
    int e0 = blk * chunk, e1 = min(e0 + chunk, E);
    for (int e = e0 + threadIdx.x; e < e1; e += 1024) {
        int d = dst[e];
        int pos = atomicAdd(&curs[d >> BSHIFT], 1);
        pairs[pos] = ((unsigned)src[e] << 7) | (unsigned)(d & 127);
    }
}

// pass D: per-bucket local hist + scan -> row_ptr AND srcs8 (byte offsets).
// Segment staged in LDS (one global pairs read instead of two).
__global__ __launch_bounds__(256) void bucket_csr_kernel(
    const unsigned* __restrict__ pairs, const int* __restrict__ offsets,
    int* __restrict__ row_ptr, int* __restrict__ srcs8, int N, int E)
{
    int b = blockIdx.x;                    // 0..NB-1
    int seg0 = offsets[b * G];
    int seg1 = (b < NB - 1) ? offsets[(b + 1) * G] : E;
    int len = seg1 - seg0;
    __shared__ int hist[128], curs[128];
    __shared__ unsigned seg[SEGCAP];
    bool fits = len <= SEGCAP;

    if (threadIdx.x < 128) hist[threadIdx.x] = 0;
    __syncthreads();
    if (fits) {
        for (int e = threadIdx.x; e < len; e += 256) {
            unsigned p = pairs[seg0 + e];
            seg[e] = p;
            atomicAdd(&hist[p & 127], 1);
        }
    } else {
        for (int e = seg0 + threadIdx.x; e < seg1; e += 256)
            atomicAdd(&hist[pairs[e] & 127], 1);
    }
    __syncthreads();
    int v = (threadIdx.x < 128) ? hist[threadIdx.x] : 0;
    if (threadIdx.x < 128) curs[threadIdx.x] = v;
    __syncthreads();
    for (int o = 1; o < 128; o <<= 1) {
        int a = 0;
        if (threadIdx.x < 128 && threadIdx.x >= o) a = curs[threadIdx.x - o];
        __syncthreads();
        if (threadIdx.x < 128) curs[threadIdx.x] += a;
        __syncthreads();
    }
    int excl = (threadIdx.x < 128) ? curs[threadIdx.x] - v : 0;
    __syncthreads();
    if (threadIdx.x < 128) {
        int node = b * 128 + threadIdx.x;
        if (node <= N) row_ptr[node] = seg0 + excl;
        curs[threadIdx.x] = excl;
    }
    __syncthreads();
    if (fits) {
        for (int e = threadIdx.x; e < len; e += 256) {
            unsigned p = seg[e];
            int pos = seg0 + atomicAdd(&curs[p & 127], 1);
            srcs8[pos] = (int)((p >> 7) << 8);
        }
    } else {
        for (int e = seg0 + threadIdx.x; e < seg1; e += 256) {
            unsigned p = pairs[e];
            int pos = seg0 + atomicAdd(&curs[p & 127], 1);
            srcs8[pos] = (int)((p >> 7) << 8);
        }
    }
}

// ---------------- MFMA GEMM, LDS-staged B; 512 thr, 128 rows/block (R16-proven) ------

template<int A_FP32>
__global__ __launch_bounds__(512) void mfma_gemm_kernel(
    const void* __restrict__ Xin,
    const _Float16* __restrict__ Wlt, const float* __restrict__ bl,
    const _Float16* __restrict__ Wrt, const float* __restrict__ br,
    _Float16* __restrict__ xl, _Float16* __restrict__ xr, int N)
{
    const int m = blockIdx.y;
    const _Float16* Wt = m ? Wrt : Wlt;

    __shared__ f16x8 Ws[F * 17];             // 128 rows x (16 data + 1 pad) granules
    for (int i = threadIdx.x; i < F * 16; i += 512) {
        int row = i >> 4, g = i & 15;
        Ws[row * 17 + g] = ((const f16x8*)Wt)[i];
    }
    __syncthreads();

    const int wid  = threadIdx.x >> 6;       // 0..7
    const int lane = threadIdx.x & 63;
    const int row0 = blockIdx.x * 128 + wid * 16;
    const int arow = lane & 15;
    const int g    = lane >> 4;              // 0..3

    int xrow = row0 + arow;
    if (xrow >= N) xrow = N - 1;             // clamp (C stores guarded)
    f16x8 af[4];
    if (A_FP32) {
        const float* xp = (const float*)Xin + (size_t)xrow * F + g * 8;
        #pragma unroll
        for (int t = 0; t < 4; ++t) {
            float4 lo = *(const float4*)(xp + t * 32);
            float4 hi = *(const float4*)(xp + t * 32 + 4);
            f16x8 a;
            a[0] = (_Float16)lo.x; a[1] = (_Float16)lo.y; a[2] = (_Float16)lo.z; a[3] = (_Float16)lo.w;
            a[4] = (_Float16)hi.x; a[5] = (_Float16)hi.y; a[6] = (_Float16)hi.z; a[7] = (_Float16)hi.w;
            af[t] = a;
        }
    } else {
        const _Float16* xp = (const _Float16*)Xin + (size_t)xrow * F + g * 8;
        #pragma unroll
        for (int t = 0; t < 4; ++t)
            af[t] = *(const f16x8*)(xp + t * 32);
    }

    f32x4 acc[8];
    #pragma unroll
    for (int nt = 0; nt < 8; ++nt) acc[nt] = (f32x4){0.f, 0.f, 0.f, 0.f};

    #pragma unroll
    for (int t = 0; t < 4; ++t)
        #pragma unroll
        for (int nt = 0; nt < 8; ++nt) {
            f16x8 b = Ws[(nt * 16 + arow) * 17 + (t * 4 + g)];
            acc[nt] = __builtin_amdgcn_mfma_f32_16x16x32_f16(af[t], b, acc[nt], 0, 0, 0);
        }

    const float* bias = m ? br : bl;
    _Float16* out = m ? xr : xl;
    #pragma unroll
    for (int nt = 0; nt < 8; ++nt) {
        int ccol = nt * 16 + (lane & 15);
        float bv = bias[ccol];
        #pragma unroll
        for (int r2 = 0; r2 < 4; ++r2) {
            int crow = row0 + (lane >> 4) * 4 + r2;
            if (crow < N)
                out[(size_t)crow * F + ccol] = (_Float16)(acc[nt][r2] + bv);
        }
    }
}

// ---------------- fused edge phase v6: v5 + fdot2 logits ----------------
// 4 nodes/wave (16-lane groups). Lane q owns channels 8q..8q+7 exclusively ->
// o[] lane-local, no epilogue combine. 4 edges in flight. Logit dot via
// v_dot2_f32_f16 (f32 accumulate, no unpack) where available.

__device__ __forceinline__ float dot2acc(f16x2 a, f16x2 b, float c) {
#if __has_builtin(__builtin_amdgcn_fdot2)
    return __builtin_amdgcn_fdot2(a, b, c, false);
#else
    return c + (float)a[0] * (float)b[0] + (float)a[1] * (float)b[1];
#endif
}

__global__ __launch_bounds__(256) void gat_edge_kernel(
    const char* __restrict__ xlh_bytes, const _Float16* __restrict__ xrh,
    const int* __restrict__ srcs8, const int* __restrict__ row_ptr,
    const _Float16* __restrict__ attH, const float* __restrict__ bias,
    float* __restrict__ outf, _Float16* __restrict__ outh,
    int N, int do_relu, int out_half)
{
    int lane = threadIdx.x;      // 0..63
    int grp  = lane >> 4;        // node group 0..3
    int q    = lane & 15;        // channel-oct: channels 8q..8q+7
    int node = blockIdx.x * 16 + threadIdx.y * 4 + grp;
    if (node >= N) return;

    f16x8 xr8 = *(const f16x8*)(xrh + (size_t)node * F + q * 8);
    f16x8 at8 = *(const f16x8*)(attH + q * 8);
    const f16x2* xr2 = (const f16x2*)&xr8;
    const f16x2* at2 = (const f16x2*)&at8;
    const f16x2 slope = {(_Float16)0.2f, (_Float16)0.2f};

    int beg = row_ptr[node], end = row_ptr[node + 1];
    float s = 0.f;
    float o[8] = {0.f, 0.f, 0.f, 0.f, 0.f, 0.f, 0.f, 0.f};

    for (int i = beg; i < end; i += 4) {
        bool vB = (i + 1) < end, vC = (i + 2) < end, vD = (i + 3) < end;
        int offA = srcs8[i];
        int offB = srcs8[vB ? i + 1 : i];
        int offC = srcs8[vC ? i + 2 : i];
        int offD = srcs8[vD ? i + 3 : i];
        f16x8 hA = *(const f16x8*)(xlh_bytes + (size_t)(unsigned)offA + q * 16);
        f16x8 hB = *(const f16x8*)(xlh_bytes + (size_t)(unsigned)offB + q * 16);
        f16x8 hC = *(const f16x8*)(xlh_bytes + (size_t)(unsigned)offC + q * 16);
        f16x8 hD = *(const f16x8*)(xlh_bytes + (size_t)(unsigned)offD + q * 16);
        const f16x2* a2 = (const f16x2*)&hA;
        const f16x2* b2 = (const f16x2*)&hB;
        const f16x2* c2 = (const f16x2*)&hC;
        const f16x2* d2 = (const f16x2*)&hD;

        float pA = 0.f, pB = 0.f, pC = 0.f, pD = 0.f;
        #pragma unroll
        for (int j = 0; j < 4; ++j) {
            f16x2 eA = a2[j] + xr2[j];
            eA = __builtin_elementwise_max(eA, eA * slope);   // leaky_relu .2
            pA = dot2acc(eA, at2[j], pA);
            f16x2 eB = b2[j] + xr2[j];
            eB = __builtin_elementwise_max(eB, eB * slope);
            pB = dot2acc(eB, at2[j], pB);
            f16x2 eC = c2[j] + xr2[j];
            eC = __builtin_elementwise_max(eC, eC * slope);
            pC = dot2acc(eC, at2[j], pC);
            f16x2 eD = d2[j] + xr2[j];
            eD = __builtin_elementwise_max(eD, eD * slope);
            pD = dot2acc(eD, at2[j], pD);
        }
        pA += __shfl_xor(pA, 1); pA += __shfl_xor(pA, 2);     // head quad reduce
        pB += __shfl_xor(pB, 1); pB += __shfl_xor(pB, 2);
        pC += __shfl_xor(pC, 1); pC += __shfl_xor(pC, 2);
        pD += __shfl_xor(pD, 1); pD += __shfl_xor(pD, 2);
        float wA = __expf(pA);
        float wB = vB ? __expf(pB) : 0.f;
        float wC = vC ? __expf(pC) : 0.f;
        float wD = vD ? __expf(pD) : 0.f;
        s += (wA + wB) + (wC + wD);
        #pragma unroll
        for (int j = 0; j < 8; ++j) {
            o[j] = fmaf(wA, (float)hA[j], o[j]);
            o[j] = fmaf(wB, (float)hB[j], o[j]);
            o[j] = fmaf(wC, (float)hC[j], o[j]);
            o[j] = fmaf(wD, (float)hD[j], o[j]);
        }
    }

    float inv = 1.f / (s + 1e-16f);
    float r[8];
    #pragma unroll
    for (int j = 0; j < 8; ++j) {
        r[j] = fmaf(o[j], inv, bias[q * 8 + j]);
        if (do_relu) r[j] = fmaxf(r[j], 0.f);
    }
    if (out_half) {
        f16x8 hv;
        #pragma unroll
        for (int j = 0; j < 8; ++j) hv[j] = (_Float16)r[j];
        *(f16x8*)(outh + (size_t)node * F + q * 8) = hv;
    } else {
        float4 lo = {r[0], r[1], r[2], r[3]};
        float4 hi = {r[4], r[5], r[6], r[7]};
        *(float4*)(outf + (size_t)node * F + q * 8) = lo;
        *(float4*)(outf + (size_t)node * F + q * 8 + 4) = hi;
    }
}

// ---------------- launch ----------------

extern "C" void kernel_launch(void* const* d_in, const int* in_sizes, int n_in,
                              void* d_out, int out_size, void* d_ws, size_t ws_size,
                              hipStream_t stream)
{
    const float* x    = (const float*)d_in[0];
    const int*   ei   = (const int*)d_in[1];
    const float* Wl1  = (const float*)d_in[2];
    const float* Wr1  = (const float*)d_in[3];
    const float* Wl2  = (const float*)d_in[4];
    const float* Wr2  = (const float*)d_in[5];
    const float* bl1  = (const float*)d_in[6];
    const float* br1  = (const float*)d_in[7];
    const float* bl2  = (const float*)d_in[8];
    const float* br2  = (const float*)d_in[9];
    const float* att1 = (const float*)d_in[10];
    const float* att2 = (const float*)d_in[11];
    const float* b1   = (const float*)d_in[12];
    const float* b2   = (const float*)d_in[13];

    const int N = in_sizes[0] / F;
    const int E = in_sizes[1] / 2;
    const int* src = ei;
    const int* dst = ei + E;

    char* ws = (char*)d_ws;
    size_t off = 0;
    auto alloc = [&](size_t bytes) -> void* {
        void* p = ws + off;
        off = (off + bytes + 255) & ~(size_t)255;
        return p;
    };
    _Float16* hh   = (_Float16*)alloc((size_t)N * F * sizeof(_Float16));
    _Float16* xlh  = (_Float16*)alloc((size_t)N * F * sizeof(_Float16));
    _Float16* xrh  = (_Float16*)alloc((size_t)N * F * sizeof(_Float16));
    _Float16* Wt1l = (_Float16*)alloc((size_t)F * F * sizeof(_Float16));
    _Float16* Wt1r = (_Float16*)alloc((size_t)F * F * sizeof(_Float16));
    _Float16* Wt2l = (_Float16*)alloc((size_t)F * F * sizeof(_Float16));
    _Float16* Wt2r = (_Float16*)alloc((size_t)F * F * sizeof(_Float16));
    _Float16* attH1 = (_Float16*)alloc(F * sizeof(_Float16));
    _Float16* attH2 = (_Float16*)alloc(F * sizeof(_Float16));
    int*      row_ptr = (int*)alloc((size_t)(N + 1) * sizeof(int));
    int*      counts  = (int*)alloc((size_t)NB * G * sizeof(int));
    int*      offsets = (int*)alloc((size_t)NB * G * sizeof(int));
    int*      done    = (int*)alloc(sizeof(int));
    unsigned* pairs   = (unsigned*)alloc((size_t)E * sizeof(unsigned));
    int*      srcs8   = (int*)alloc((size_t)E * sizeof(int));

    // bucketed CSR build + weight/att convert (3 dispatches + 4B memset)
    const int chunk = (E + G - 1) / G;
    hipMemsetAsync(done, 0, sizeof(int), stream);
    hist_convw_scan_kernel<<<G + 65, 1024, 0, stream>>>(dst, counts, E, chunk,
                                                        Wl1, Wr1, Wl2, Wr2,
                                                        Wt1l, Wt1r, Wt2l, Wt2r,
                                                        att1, att2, attH1, attH2,
                                                        done, offsets);
    bucket_scatter_kernel<<<G, 1024, 0, stream>>>(src, dst, offsets, pairs, E, chunk);
    bucket_csr_kernel<<<NB, 256, 0, stream>>>(pairs, offsets, row_ptr, srcs8, N, E);

    const int gemm_blocks = (N + 127) / 128;
    dim3 gemm_grid(gemm_blocks, 2);
    dim3 eb(64, 4);
    const int edge_blocks = (N + 15) / 16;

    // layer 1 (A fp32, converted inline)
    mfma_gemm_kernel<1><<<gemm_grid, 512, 0, stream>>>(
        x, Wt1l, bl1, Wt1r, br1, xlh, xrh, N);
    gat_edge_kernel<<<edge_blocks, eb, 0, stream>>>(
        (const char*)xlh, xrh, srcs8, row_ptr, attH1, b1,
        nullptr, hh, N, 1, 1);

    // layer 2 (A fp16 from edge layer 1)
    mfma_gemm_kernel<0><<<gemm_grid, 512, 0, stream>>>(
        hh, Wt2l, bl2, Wt2r, br2, xlh, xrh, N);
    gat_edge_kernel<<<edge_blocks, eb, 0, stream>>>(
        (const char*)xlh, xrh, srcs8, row_ptr, attH2, b2,
        (float*)d_out, nullptr, N, 0, 0);
}

// Round 18
// 150.631 us; speedup vs baseline: 1.1718x; 1.1718x over previous
//
#include <hip/hip_runtime.h>
#include <hip/hip_bf16.h>
#include <hip/hip_fp16.h>
#include <float.h>

#define F 128          // hidden = H*C
#define HEADS 4
#define CPH 32

// bucket sort params: bucket = dst>>7 (N=50000 <= 65536), 512 buckets,
// G=64 edge-chunk blocks -> counts matrix 512x64 = 32768.
#define NB 512
#define BSHIFT 7
#define G 64
#define SEGCAP 5120    // LDS staging cap for a bucket segment (mean 1562, P(>5120)~0)

using f16x2 = __attribute__((ext_vector_type(2))) _Float16;
using f16x8 = __attribute__((ext_vector_type(8))) _Float16;
using f32x4 = __attribute__((ext_vector_type(4))) float;

// ---------------- fused bucket-hist + weight/att convert ----------------
// R17 lesson: do NOT fuse the scan via done-ticket+threadfence (cross-XCD fence
// cost 42us) and do NOT memset 4B in the graph (fill dispatch ~45us). Separate
// dispatches are cheaper.

__global__ __launch_bounds__(1024) void hist_convw_kernel(
    const int* __restrict__ dst, int* __restrict__ counts, int E, int chunk,
    const float* __restrict__ W0, const float* __restrict__ W1,
    const float* __restrict__ W2, const float* __restrict__ W3,
    _Float16* __restrict__ T0, _Float16* __restrict__ T1,
    _Float16* __restrict__ T2, _Float16* __restrict__ T3,
    const float* __restrict__ att1, const float* __restrict__ att2,
    _Float16* __restrict__ attH1, _Float16* __restrict__ attH2)
{
    __shared__ int hist[NB];
    if (blockIdx.x < G) {
        int blk = blockIdx.x;
        for (int b = threadIdx.x; b < NB; b += 1024) hist[b] = 0;
        __syncthreads();
        int e0 = blk * chunk, e1 = min(e0 + chunk, E);
        for (int e = e0 + threadIdx.x; e < e1; e += 1024)
            atomicAdd(&hist[dst[e] >> BSHIFT], 1);
        __syncthreads();
        for (int b = threadIdx.x; b < NB; b += 1024)
            counts[b * G + blk] = hist[b];
    } else if (blockIdx.x < G + 64) {
        int b = blockIdx.x - G;                       // 0..63
        int m = b >> 4;
        int tid = (b & 15) * 1024 + threadIdx.x;      // 0..16383 = n*128+k
        int n = tid >> 7, k = tid & 127;
        const float* W = m == 0 ? W0 : m == 1 ? W1 : m == 2 ? W2 : W3;
        _Float16*    T = m == 0 ? T0 : m == 1 ? T1 : m == 2 ? T2 : T3;
        T[tid] = (_Float16)W[k * F + n];
    } else {
        if (threadIdx.x < 128)      attH1[threadIdx.x] = (_Float16)att1[threadIdx.x];
        else if (threadIdx.x < 256) attH2[threadIdx.x - 128] = (_Float16)att2[threadIdx.x - 128];
    }
}

// ---------------- fused single-block scan of counts (32768 = 1024 x 32) ----------------

__global__ __launch_bounds__(1024) void scan_fused_kernel(
    const int* __restrict__ counts, int* __restrict__ offsets)
{
    __shared__ int tmp[1024];
    int t = threadIdx.x;
    int loc[32];
    int s = 0;
    #pragma unroll
    for (int j = 0; j < 32; ++j) { loc[j] = s; s += counts[t * 32 + j]; }
    tmp[t] = s;
    __syncthreads();
    for (int o = 1; o < 1024; o <<= 1) {
        int a = (t >= o) ? tmp[t - o] : 0;
        __syncthreads();
        tmp[t] += a;
        __syncthreads();
    }
    int excl = tmp[t] - s;
    #pragma unroll
    for (int j = 0; j < 32; ++j) offsets[t * 32 + j] = excl + loc[j];
}

// pass C: scatter PACKED (src<<7)|(dst&127) into bucket-sorted order (4B/edge)
__global__ __launch_bounds__(1024) void bucket_scatter_kernel(
    const int* __restrict__ src, const int* __restrict__ dst,
    const int* __restrict__ offsets, unsigned* __restrict__ pairs, int E, int chunk)
{
    __shared__ int curs[NB];
    int blk = blockIdx.x;
    for (int b = threadIdx.x; b < NB; b += 1024) curs[b] = offsets[b * G + blk];
    __syncthreads();
    int e0 = blk * chunk, e1 = min(e0 + chunk, E);
    for (int e = e0 + threadIdx.x; e < e1; e += 1024) {
        int d = dst[e];
        int pos = atomicAdd(&curs[d >> BSHIFT], 1);
        pairs[pos] = ((unsigned)src[e] << 7) | (unsigned)(d & 127);
    }
}

// pass D: per-bucket local hist + scan -> row_ptr AND srcs8 (byte offsets).
// Segment staged in LDS (one global pairs read instead of two).
__global__ __launch_bounds__(256) void bucket_csr_kernel(
    const unsigned* __restrict__ pairs, const int* __restrict__ offsets,
    int* __restrict__ row_ptr, int* __restrict__ srcs8, int N, int E)
{
    int b = blockIdx.x;                    // 0..NB-1
    int seg0 = offsets[b * G];
    int seg1 = (b < NB - 1) ? offsets[(b + 1) * G] : E;
    int len = seg1 - seg0;
    __shared__ int hist[128], curs[128];
    __shared__ unsigned seg[SEGCAP];
    bool fits = len <= SEGCAP;

    if (threadIdx.x < 128) hist[threadIdx.x] = 0;
    __syncthreads();
    if (fits) {
        for (int e = threadIdx.x; e < len; e += 256) {
            unsigned p = pairs[seg0 + e];
            seg[e] = p;
            atomicAdd(&hist[p & 127], 1);
        }
    } else {
        for (int e = seg0 + threadIdx.x; e < seg1; e += 256)
            atomicAdd(&hist[pairs[e] & 127], 1);
    }
    __syncthreads();
    int v = (threadIdx.x < 128) ? hist[threadIdx.x] : 0;
    if (threadIdx.x < 128) curs[threadIdx.x] = v;
    __syncthreads();
    for (int o = 1; o < 128; o <<= 1) {
        int a = 0;
        if (threadIdx.x < 128 && threadIdx.x >= o) a = curs[threadIdx.x - o];
        __syncthreads();
        if (threadIdx.x < 128) curs[threadIdx.x] += a;
        __syncthreads();
    }
    int excl = (threadIdx.x < 128) ? curs[threadIdx.x] - v : 0;
    __syncthreads();
    if (threadIdx.x < 128) {
        int node = b * 128 + threadIdx.x;
        if (node <= N) row_ptr[node] = seg0 + excl;
        curs[threadIdx.x] = excl;
    }
    __syncthreads();
    if (fits) {
        for (int e = threadIdx.x; e < len; e += 256) {
            unsigned p = seg[e];
            int pos = seg0 + atomicAdd(&curs[p & 127], 1);
            srcs8[pos] = (int)((p >> 7) << 8);
        }
    } else {
        for (int e = seg0 + threadIdx.x; e < seg1; e += 256) {
            unsigned p = pairs[e];
            int pos = seg0 + atomicAdd(&curs[p & 127], 1);
            srcs8[pos] = (int)((p >> 7) << 8);
        }
    }
}

// ---------------- MFMA GEMM, LDS-staged B; 512 thr, 128 rows/block ----------------
// grid (nb, 2): blockIdx.y = matrix (0: Wl -> xl, 1: Wr -> xr), both fp16 out.
// 8 waves x 16 rows = 128 rows/block: one W-stage amortized over 2x rows.
// W^T in LDS with 17-granule row pad.
// A/B share k-slot map (k = t*32+g*8+j); C/D: col=lane&15, row=(lane>>4)*4+reg.

template<int A_FP32>
__global__ __launch_bounds__(512) void mfma_gemm_kernel(
    const void* __restrict__ Xin,
    const _Float16* __restrict__ Wlt, const float* __restrict__ bl,
    const _Float16* __restrict__ Wrt, const float* __restrict__ br,
    _Float16* __restrict__ xl, _Float16* __restrict__ xr, int N)
{
    const int m = blockIdx.y;
    const _Float16* Wt = m ? Wrt : Wlt;

    __shared__ f16x8 Ws[F * 17];             // 128 rows x (16 data + 1 pad) granules
    for (int i = threadIdx.x; i < F * 16; i += 512) {
        int row = i >> 4, g = i & 15;
        Ws[row * 17 + g] = ((const f16x8*)Wt)[i];
    }
    __syncthreads();

    const int wid  = threadIdx.x >> 6;       // 0..7
    const int lane = threadIdx.x & 63;
    const int row0 = blockIdx.x * 128 + wid * 16;
    const int arow = lane & 15;
    const int g    = lane >> 4;              // 0..3

    int xrow = row0 + arow;
    if (xrow >= N) xrow = N - 1;             // clamp (C stores guarded)
    f16x8 af[4];
    if (A_FP32) {
        const float* xp = (const float*)Xin + (size_t)xrow * F + g * 8;
        #pragma unroll
        for (int t = 0; t < 4; ++t) {
            float4 lo = *(const float4*)(xp + t * 32);
            float4 hi = *(const float4*)(xp + t * 32 + 4);
            f16x8 a;
            a[0] = (_Float16)lo.x; a[1] = (_Float16)lo.y; a[2] = (_Float16)lo.z; a[3] = (_Float16)lo.w;
            a[4] = (_Float16)hi.x; a[5] = (_Float16)hi.y; a[6] = (_Float16)hi.z; a[7] = (_Float16)hi.w;
            af[t] = a;
        }
    } else {
        const _Float16* xp = (const _Float16*)Xin + (size_t)xrow * F + g * 8;
        #pragma unroll
        for (int t = 0; t < 4; ++t)
            af[t] = *(const f16x8*)(xp + t * 32);
    }

    f32x4 acc[8];
    #pragma unroll
    for (int nt = 0; nt < 8; ++nt) acc[nt] = (f32x4){0.f, 0.f, 0.f, 0.f};

    #pragma unroll
    for (int t = 0; t < 4; ++t)
        #pragma unroll
        for (int nt = 0; nt < 8; ++nt) {
            f16x8 b = Ws[(nt * 16 + arow) * 17 + (t * 4 + g)];
            acc[nt] = __builtin_amdgcn_mfma_f32_16x16x32_f16(af[t], b, acc[nt], 0, 0, 0);
        }

    const float* bias = m ? br : bl;
    _Float16* out = m ? xr : xl;
    #pragma unroll
    for (int nt = 0; nt < 8; ++nt) {
        int ccol = nt * 16 + (lane & 15);
        float bv = bias[ccol];
        #pragma unroll
        for (int r2 = 0; r2 < 4; ++r2) {
            int crow = row0 + (lane >> 4) * 4 + r2;
            if (crow < N)
                out[(size_t)crow * F + ccol] = (_Float16)(acc[nt][r2] + bv);
        }
    }
}

// ---------------- fused edge phase v5 (R15/R16-proven): 16-lane groups, 4 in flight --

__global__ __launch_bounds__(256) void gat_edge_kernel(
    const char* __restrict__ xlh_bytes, const _Float16* __restrict__ xrh,
    const int* __restrict__ srcs8, const int* __restrict__ row_ptr,
    const _Float16* __restrict__ attH, const float* __restrict__ bias,
    float* __restrict__ outf, _Float16* __restrict__ outh,
    int N, int do_relu, int out_half)
{
    int lane = threadIdx.x;      // 0..63
    int grp  = lane >> 4;        // node group 0..3
    int q    = lane & 15;        // channel-oct: channels 8q..8q+7
    int node = blockIdx.x * 16 + threadIdx.y * 4 + grp;
    if (node >= N) return;

    f16x8 xr8 = *(const f16x8*)(xrh + (size_t)node * F + q * 8);
    f16x8 at8 = *(const f16x8*)(attH + q * 8);
    const f16x2* xr2 = (const f16x2*)&xr8;
    const f16x2* at2 = (const f16x2*)&at8;
    const f16x2 slope = {(_Float16)0.2f, (_Float16)0.2f};

    int beg = row_ptr[node], end = row_ptr[node + 1];
    float s = 0.f;
    float o[8] = {0.f, 0.f, 0.f, 0.f, 0.f, 0.f, 0.f, 0.f};

    for (int i = beg; i < end; i += 4) {
        bool vB = (i + 1) < end, vC = (i + 2) < end, vD = (i + 3) < end;
        int offA = srcs8[i];
        int offB = srcs8[vB ? i + 1 : i];
        int offC = srcs8[vC ? i + 2 : i];
        int offD = srcs8[vD ? i + 3 : i];
        f16x8 hA = *(const f16x8*)(xlh_bytes + (size_t)(unsigned)offA + q * 16);
        f16x8 hB = *(const f16x8*)(xlh_bytes + (size_t)(unsigned)offB + q * 16);
        f16x8 hC = *(const f16x8*)(xlh_bytes + (size_t)(unsigned)offC + q * 16);
        f16x8 hD = *(const f16x8*)(xlh_bytes + (size_t)(unsigned)offD + q * 16);
        const f16x2* a2 = (const f16x2*)&hA;
        const f16x2* b2 = (const f16x2*)&hB;
        const f16x2* c2 = (const f16x2*)&hC;
        const f16x2* d2 = (const f16x2*)&hD;

        f16x2 pA2 = {(_Float16)0.f, (_Float16)0.f};
        f16x2 pB2 = pA2, pC2 = pA2, pD2 = pA2;
        #pragma unroll
        for (int j = 0; j < 4; ++j) {
            f16x2 eA = a2[j] + xr2[j];
            eA = __builtin_elementwise_max(eA, eA * slope);
            pA2 += eA * at2[j];
            f16x2 eB = b2[j] + xr2[j];
            eB = __builtin_elementwise_max(eB, eB * slope);
            pB2 += eB * at2[j];
            f16x2 eC = c2[j] + xr2[j];
            eC = __builtin_elementwise_max(eC, eC * slope);
            pC2 += eC * at2[j];
            f16x2 eD = d2[j] + xr2[j];
            eD = __builtin_elementwise_max(eD, eD * slope);
            pD2 += eD * at2[j];
        }
        float pA = (float)pA2[0] + (float)pA2[1];
        float pB = (float)pB2[0] + (float)pB2[1];
        float pC = (float)pC2[0] + (float)pC2[1];
        float pD = (float)pD2[0] + (float)pD2[1];
        pA += __shfl_xor(pA, 1); pA += __shfl_xor(pA, 2);
        pB += __shfl_xor(pB, 1); pB += __shfl_xor(pB, 2);
        pC += __shfl_xor(pC, 1); pC += __shfl_xor(pC, 2);
        pD += __shfl_xor(pD, 1); pD += __shfl_xor(pD, 2);
        float wA = __expf(pA);
        float wB = vB ? __expf(pB) : 0.f;
        float wC = vC ? __expf(pC) : 0.f;
        float wD = vD ? __expf(pD) : 0.f;
        s += (wA + wB) + (wC + wD);
        #pragma unroll
        for (int j = 0; j < 8; ++j) {
            o[j] = fmaf(wA, (float)hA[j], o[j]);
            o[j] = fmaf(wB, (float)hB[j], o[j]);
            o[j] = fmaf(wC, (float)hC[j], o[j]);
            o[j] = fmaf(wD, (float)hD[j], o[j]);
        }
    }

    float inv = 1.f / (s + 1e-16f);
    float r[8];
    #pragma unroll
    for (int j = 0; j < 8; ++j) {
        r[j] = fmaf(o[j], inv, bias[q * 8 + j]);
        if (do_relu) r[j] = fmaxf(r[j], 0.f);
    }
    if (out_half) {
        f16x8 hv;
        #pragma unroll
        for (int j = 0; j < 8; ++j) hv[j] = (_Float16)r[j];
        *(f16x8*)(outh + (size_t)node * F + q * 8) = hv;
    } else {
        float4 lo = {r[0], r[1], r[2], r[3]};
        float4 hi = {r[4], r[5], r[6], r[7]};
        *(float4*)(outf + (size_t)node * F + q * 8) = lo;
        *(float4*)(outf + (size_t)node * F + q * 8 + 4) = hi;
    }
}

// ---------------- launch ----------------

extern "C" void kernel_launch(void* const* d_in, const int* in_sizes, int n_in,
                              void* d_out, int out_size, void* d_ws, size_t ws_size,
                              hipStream_t stream)
{
    const float* x    = (const float*)d_in[0];
    const int*   ei   = (const int*)d_in[1];
    const float* Wl1  = (const float*)d_in[2];
    const float* Wr1  = (const float*)d_in[3];
    const float* Wl2  = (const float*)d_in[4];
    const float* Wr2  = (const float*)d_in[5];
    const float* bl1  = (const float*)d_in[6];
    const float* br1  = (const float*)d_in[7];
    const float* bl2  = (const float*)d_in[8];
    const float* br2  = (const float*)d_in[9];
    const float* att1 = (const float*)d_in[10];
    const float* att2 = (const float*)d_in[11];
    const float* b1   = (const float*)d_in[12];
    const float* b2   = (const float*)d_in[13];

    const int N = in_sizes[0] / F;
    const int E = in_sizes[1] / 2;
    const int* src = ei;
    const int* dst = ei + E;

    char* ws = (char*)d_ws;
    size_t off = 0;
    auto alloc = [&](size_t bytes) -> void* {
        void* p = ws + off;
        off = (off + bytes + 255) & ~(size_t)255;
        return p;
    };
    _Float16* hh   = (_Float16*)alloc((size_t)N * F * sizeof(_Float16));
    _Float16* xlh  = (_Float16*)alloc((size_t)N * F * sizeof(_Float16));
    _Float16* xrh  = (_Float16*)alloc((size_t)N * F * sizeof(_Float16));
    _Float16* Wt1l = (_Float16*)alloc((size_t)F * F * sizeof(_Float16));
    _Float16* Wt1r = (_Float16*)alloc((size_t)F * F * sizeof(_Float16));
    _Float16* Wt2l = (_Float16*)alloc((size_t)F * F * sizeof(_Float16));
    _Float16* Wt2r = (_Float16*)alloc((size_t)F * F * sizeof(_Float16));
    _Float16* attH1 = (_Float16*)alloc(F * sizeof(_Float16));
    _Float16* attH2 = (_Float16*)alloc(F * sizeof(_Float16));
    int*      row_ptr = (int*)alloc((size_t)(N + 1) * sizeof(int));
    int*      counts  = (int*)alloc((size_t)NB * G * sizeof(int));
    int*      offsets = (int*)alloc((size_t)NB * G * sizeof(int));
    unsigned* pairs   = (unsigned*)alloc((size_t)E * sizeof(unsigned));
    int*      srcs8   = (int*)alloc((size_t)E * sizeof(int));

    // bucketed CSR build + weight/att convert (4 dispatches)
    const int chunk = (E + G - 1) / G;
    hist_convw_kernel<<<G + 65, 1024, 0, stream>>>(dst, counts, E, chunk,
                                                   Wl1, Wr1, Wl2, Wr2,
                                                   Wt1l, Wt1r, Wt2l, Wt2r,
                                                   att1, att2, attH1, attH2);
    scan_fused_kernel<<<1, 1024, 0, stream>>>(counts, offsets);
    bucket_scatter_kernel<<<G, 1024, 0, stream>>>(src, dst, offsets, pairs, E, chunk);
    bucket_csr_kernel<<<NB, 256, 0, stream>>>(pairs, offsets, row_ptr, srcs8, N, E);

    const int gemm_blocks = (N + 127) / 128;
    dim3 gemm_grid(gemm_blocks, 2);
    dim3 eb(64, 4);
    const int edge_blocks = (N + 15) / 16;

    // layer 1 (A fp32, converted inline)
    mfma_gemm_kernel<1><<<gemm_grid, 512, 0, stream>>>(
        x, Wt1l, bl1, Wt1r, br1, xlh, xrh, N);
    gat_edge_kernel<<<edge_blocks, eb, 0, stream>>>(
        (const char*)xlh, xrh, srcs8, row_ptr, attH1, b1,
        nullptr, hh, N, 1, 1);

    // layer 2 (A fp16 from edge layer 1)
    mfma_gemm_kernel<0><<<gemm_grid, 512, 0, stream>>>(
        hh, Wt2l, bl2, Wt2r, br2, xlh, xrh, N);
    gat_edge_kernel<<<edge_blocks, eb, 0, stream>>>(
        (const char*)xlh, xrh, srcs8, row_ptr, attH2, b2,
        (float*)d_out, nullptr, N, 0, 0);
}